// Round 2
// baseline (277.493 us; speedup 1.0000x reference)
//
#include <hip/hip_runtime.h>
#include <hip/hip_bf16.h>
#include <math.h>

typedef __bf16 bf16_t;
typedef bf16_t bf16x8 __attribute__((ext_vector_type(8)));
typedef bf16_t bf16x4 __attribute__((ext_vector_type(4)));
typedef float f32x4 __attribute__((ext_vector_type(4)));

#define DEV_INLINE __device__ __forceinline__

constexpr int B_ = 4, T_ = 2048, DM = 1024, NH = 8, RK = 64;
constexpr int BT = B_ * T_;        // 8192
constexpr int QC = NH * RK;        // 512
// softmax scale baked into Wq_eff: (1/sqrt(256)) * log2(e)
#define QK_SCALE 0.09016844f

// ---------------------------------------------------------------- cast f32->bf16
__global__ void cast_f32_bf16(const float* __restrict__ in, bf16_t* __restrict__ out, int n) {
  int i = (blockIdx.x * blockDim.x + threadIdx.x) * 4;
  if (i >= n) return;
  const float4 v = *reinterpret_cast<const float4*>(in + i);
  bf16x4 o;
  o[0] = (bf16_t)v.x; o[1] = (bf16_t)v.y; o[2] = (bf16_t)v.z; o[3] = (bf16_t)v.w;
  *reinterpret_cast<bf16x4*>(out + i) = o;
}

// ---------------------------------------------------------------- Wq_eff[(h*64+r), m] = scale * sum_d Wk_up[(h*256+d)*64+r] * Wq[(h*256+d)*1024+m]
__global__ void build_wq_eff(const float* __restrict__ Wku, const float* __restrict__ Wq,
                             bf16_t* __restrict__ out) {
  const int m = blockIdx.x * 256 + threadIdx.x;   // [0,1024)
  const int h = blockIdx.y;                       // [0,8)
  const int r0 = blockIdx.z * 8;                  // [0,64) step 8
  float s[8] = {};
  const float* wk = Wku + (size_t)h * 256 * 64 + r0;
  const float* wq = Wq + (size_t)h * 256 * 1024 + m;
  for (int d = 0; d < 256; ++d) {
    float qv = wq[(size_t)d * 1024];
#pragma unroll
    for (int j = 0; j < 8; ++j) s[j] += wk[d * 64 + j] * qv;
  }
#pragma unroll
  for (int j = 0; j < 8; ++j)
    out[(size_t)(h * 64 + r0 + j) * 1024 + m] = (bf16_t)(s[j] * QK_SCALE);
}

// ---------------------------------------------------------------- W_eff[m*512 + h*64 + r] = sum_d Wo[m*2048 + h*256 + d] * Wv_up[(h*256+d)*64 + r]
__global__ void build_w_eff(const float* __restrict__ Wo, const float* __restrict__ Wvu,
                            bf16_t* __restrict__ out) {
  const int m = blockIdx.x;                        // [0,1024)
  const int h = blockIdx.y * 4 + (threadIdx.x >> 6);
  const int r = threadIdx.x & 63;
  float s = 0.f;
  const float* wo = Wo + (size_t)m * 2048 + h * 256;
  const float* wv = Wvu + (size_t)h * 256 * 64 + r;
  for (int d = 0; d < 256; ++d) s += wo[d] * wv[d * 64];
  out[(size_t)m * 512 + h * 64 + r] = (bf16_t)s;
}

// ---------------------------------------------------------------- transpose c: cT[b][r][t] = c[b][t][r]
__global__ void transpose_c(const bf16_t* __restrict__ c, bf16_t* __restrict__ cT) {
  __shared__ bf16_t tile[64][65];
  const int b = blockIdx.y;
  const int t0 = blockIdx.x * 64;
  const int tx = threadIdx.x & 63;
  const int ty = threadIdx.x >> 6;   // 0..3
#pragma unroll
  for (int i = 0; i < 16; ++i) {
    int t = ty * 16 + i;
    tile[t][tx] = c[((size_t)b * T_ + t0 + t) * RK + tx];
  }
  __syncthreads();
#pragma unroll
  for (int i = 0; i < 16; ++i) {
    int r = ty * 16 + i;
    cT[((size_t)b * RK + r) * T_ + t0 + tx] = tile[tx][r];
  }
}

// ---------------------------------------------------------------- GEMM C[M,N] = A[M,K] * B[N,K]^T (bf16 in, f32 acc)
DEV_INLINE void storeC(float* p, float v) { *p = v; }
DEV_INLINE void storeC(bf16_t* p, float v) { *p = (bf16_t)v; }

DEV_INLINE void async_load16(const void* g, void* l) {
  __builtin_amdgcn_global_load_lds((__attribute__((address_space(1))) void*)g,
                                   (__attribute__((address_space(3))) void*)l, 16, 0, 0);
}

template <typename OutT>
__global__ __launch_bounds__(256) void gemm_bt(const bf16_t* __restrict__ A,
                                               const bf16_t* __restrict__ Bm,
                                               OutT* __restrict__ C, int M, int N, int K) {
  __shared__ bf16_t lA[128 * 32];
  __shared__ bf16_t lB[128 * 32];
  const int tid = threadIdx.x;
  const int lane = tid & 63;
  const int w = tid >> 6;
  const int lo = lane & 15, hi = lane >> 4;
  const int wr = w >> 1, wc = w & 1;
  const size_t row0 = (size_t)blockIdx.x * 128;
  const size_t col0 = (size_t)blockIdx.y * 128;
  const int w64 = w * 64;
  f32x4 acc[4][4] = {};

  for (int k0 = 0; k0 < K; k0 += 32) {
    __syncthreads();
#pragma unroll
    for (int j = 0; j < 2; ++j) {
      const int chunk = j * 256 + w64 + lane;
      const int r = chunk >> 2;
      const int kk = (chunk & 3) * 8;
      const bf16_t* gA = A + (row0 + r) * K + (k0 + kk);
      async_load16(gA, &lA[(size_t)(j * 256 + w64) * 8]);
      size_t rB = col0 + r;
      if (rB >= (size_t)N) rB = N - 1;
      const bf16_t* gB = Bm + rB * K + (k0 + kk);
      async_load16(gB, &lB[(size_t)(j * 256 + w64) * 8]);
    }
    __syncthreads();
    const bf16x8* pA = reinterpret_cast<const bf16x8*>(lA);
    const bf16x8* pB = reinterpret_cast<const bf16x8*>(lB);
    bf16x8 af[4], bfr[4];
#pragma unroll
    for (int m = 0; m < 4; ++m) af[m] = pA[(wr * 64 + m * 16 + lo) * 4 + hi];
#pragma unroll
    for (int n = 0; n < 4; ++n) bfr[n] = pB[(wc * 64 + n * 16 + lo) * 4 + hi];
#pragma unroll
    for (int m = 0; m < 4; ++m)
#pragma unroll
      for (int n = 0; n < 4; ++n)
        acc[m][n] = __builtin_amdgcn_mfma_f32_16x16x32_bf16(af[m], bfr[n], acc[m][n], 0, 0, 0);
  }
#pragma unroll
  for (int m = 0; m < 4; ++m)
#pragma unroll
    for (int n = 0; n < 4; ++n)
#pragma unroll
      for (int q = 0; q < 4; ++q) {
        const size_t row = row0 + wr * 64 + m * 16 + hi * 4 + q;
        const size_t col = col0 + wc * 64 + n * 16 + lo;
        if ((int)col < N) storeC(&C[row * N + col], acc[m][n][q]);
      }
}

// ---------------------------------------------------------------- flash attention, scores in exp2 domain
// 64 q-rows per block; wave w: q-half (w>>1, 32 rows), kv-half (w&1).
// Qt [BT, 512] (col = h*64+r, pre-scaled), c [BT, 64], cT [B][64][T], U [BT, 512]
__global__ __launch_bounds__(256) void attn_kernel(const bf16_t* __restrict__ Qt,
                                                   const bf16_t* __restrict__ Cl,
                                                   const bf16_t* __restrict__ CT,
                                                   bf16_t* __restrict__ U) {
  __shared__ bf16_t Pl[4][16][40];
  __shared__ float Als[2][32][65];
  __shared__ float Ml[4][2][16];
  __shared__ float Ll[4][2][16];
  const int tid = threadIdx.x;
  const int w = tid >> 6, lane = tid & 63;
  const int lo = lane & 15, hi = lane >> 4;
  const int qh = w >> 1, kvh = w & 1;
  const int b = blockIdx.z, h = blockIdx.y;
  const int q0 = blockIdx.x * 64;
  const size_t qrow = (size_t)b * T_ + q0 + qh * 32;

  const bf16_t* cbase = Cl + (size_t)b * T_ * RK;
  const bf16_t* ctbase = CT + (size_t)b * RK * T_;

  // Q fragments: qf[rowset][kchunk]
  bf16x8 qf[2][2];
#pragma unroll
  for (int rs = 0; rs < 2; ++rs)
#pragma unroll
    for (int c0 = 0; c0 < 2; ++c0)
      qf[rs][c0] = *reinterpret_cast<const bf16x8*>(
          Qt + (qrow + rs * 16 + lo) * QC + h * RK + c0 * 32 + hi * 8);

  f32x4 acc[2][4] = {};
  float m_r[2][4], l_r[2][4];
#pragma unroll
  for (int rs = 0; rs < 2; ++rs)
#pragma unroll
    for (int q = 0; q < 4; ++q) { m_r[rs][q] = -INFINITY; l_r[rs][q] = 0.f; }

  for (int it = 0; it < T_ / 64; ++it) {
    const int kv0 = it * 64 + kvh * 32;
    // ---- K fragments (shared across both rowsets)
    bf16x8 kf[2][2];
#pragma unroll
    for (int n = 0; n < 2; ++n)
#pragma unroll
      for (int c0 = 0; c0 < 2; ++c0)
        kf[n][c0] = *reinterpret_cast<const bf16x8*>(
            cbase + (size_t)(kv0 + n * 16 + lo) * RK + c0 * 32 + hi * 8);
    // ---- V fragments (shared across both rowsets)
    bf16x8 vf[4];
#pragma unroll
    for (int n = 0; n < 4; ++n)
      vf[n] = *reinterpret_cast<const bf16x8*>(
          ctbase + (size_t)(n * 16 + lo) * T_ + kv0 + hi * 8);

#pragma unroll
    for (int rs = 0; rs < 2; ++rs) {
      f32x4 s[2] = {};
#pragma unroll
      for (int n = 0; n < 2; ++n)
#pragma unroll
        for (int c0 = 0; c0 < 2; ++c0)
          s[n] = __builtin_amdgcn_mfma_f32_16x16x32_bf16(qf[rs][c0], kf[n][c0], s[n], 0, 0, 0);

      // ---- row max (only cross-lane reduce left in the loop)
      float mx[4];
#pragma unroll
      for (int q = 0; q < 4; ++q) mx[q] = fmaxf(s[0][q], s[1][q]);
#pragma unroll
      for (int msk = 1; msk < 16; msk <<= 1)
#pragma unroll
        for (int q = 0; q < 4; ++q) mx[q] = fmaxf(mx[q], __shfl_xor(mx[q], msk));

      int grow = 0;
#pragma unroll
      for (int q = 0; q < 4; ++q) grow |= (mx[q] > m_r[rs][q]);
      grow = __any(grow);

      float ps[2][4];
      if (grow) {
#pragma unroll
        for (int q = 0; q < 4; ++q) {
          const float mn = fmaxf(m_r[rs][q], mx[q]);
          const float al = exp2f(m_r[rs][q] - mn);
          m_r[rs][q] = mn;
          ps[0][q] = exp2f(s[0][q] - mn);
          ps[1][q] = exp2f(s[1][q] - mn);
          l_r[rs][q] = l_r[rs][q] * al + ps[0][q] + ps[1][q];   // per-lane partial sum
#pragma unroll
          for (int n = 0; n < 4; ++n) acc[rs][n][q] *= al;
        }
      } else {
#pragma unroll
        for (int q = 0; q < 4; ++q) {
          ps[0][q] = exp2f(s[0][q] - m_r[rs][q]);
          ps[1][q] = exp2f(s[1][q] - m_r[rs][q]);
          l_r[rs][q] += ps[0][q] + ps[1][q];
        }
      }

      // ---- P transpose through per-wave LDS (no cross-wave sharing -> no barrier)
      asm volatile("s_waitcnt lgkmcnt(0)" ::: "memory");  // prev pa reads done
#pragma unroll
      for (int n = 0; n < 2; ++n)
#pragma unroll
        for (int q = 0; q < 4; ++q)
          Pl[w][hi * 4 + q][n * 16 + lo] = (bf16_t)ps[n][q];
      asm volatile("s_waitcnt lgkmcnt(0)" ::: "memory");  // P writes visible wave-wide
      __builtin_amdgcn_sched_barrier(0);

      const bf16x8 pa = *reinterpret_cast<const bf16x8*>(&Pl[w][lo][hi * 8]);
#pragma unroll
      for (int n = 0; n < 4; ++n)
        acc[rs][n] = __builtin_amdgcn_mfma_f32_16x16x32_bf16(pa, vf[n], acc[rs][n], 0, 0, 0);
    }
  }

  // ---- finalize per-lane partial l: reduce across the 16 lo-lanes (once)
#pragma unroll
  for (int rs = 0; rs < 2; ++rs)
#pragma unroll
    for (int msk = 1; msk < 16; msk <<= 1)
#pragma unroll
      for (int q = 0; q < 4; ++q) l_r[rs][q] += __shfl_xor(l_r[rs][q], msk);

  // ---- exchange m/l with kv-partner wave
  if (lo == 0) {
#pragma unroll
    for (int rs = 0; rs < 2; ++rs)
#pragma unroll
      for (int q = 0; q < 4; ++q) {
        Ml[w][rs][hi * 4 + q] = m_r[rs][q];
        Ll[w][rs][hi * 4 + q] = l_r[rs][q];
      }
  }
  __syncthreads();
  const int pw = w ^ 1;
  float f_[2][4], lst[2][4];
#pragma unroll
  for (int rs = 0; rs < 2; ++rs)
#pragma unroll
    for (int q = 0; q < 4; ++q) {
      const float m2 = Ml[pw][rs][hi * 4 + q];
      const float l2 = Ll[pw][rs][hi * 4 + q];
      const float ms = fmaxf(m_r[rs][q], m2);
      f_[rs][q] = exp2f(m_r[rs][q] - ms);
      const float f2 = exp2f(m2 - ms);
      lst[rs][q] = l_r[rs][q] * f_[rs][q] + l2 * f2;
    }
  if (kvh == 1) {
#pragma unroll
    for (int rs = 0; rs < 2; ++rs)
#pragma unroll
      for (int n = 0; n < 4; ++n)
#pragma unroll
        for (int q = 0; q < 4; ++q)
          Als[qh][rs * 16 + hi * 4 + q][n * 16 + lo] = acc[rs][n][q] * f_[rs][q];
  }
  __syncthreads();
  if (kvh == 0) {
#pragma unroll
    for (int rs = 0; rs < 2; ++rs)
#pragma unroll
      for (int q = 0; q < 4; ++q) {
        const float inv = 1.0f / lst[rs][q];
#pragma unroll
        for (int n = 0; n < 4; ++n) {
          const float v = acc[rs][n][q] * f_[rs][q] + Als[qh][rs * 16 + hi * 4 + q][n * 16 + lo];
          U[(qrow + rs * 16 + hi * 4 + q) * QC + h * RK + n * 16 + lo] = (bf16_t)(v * inv);
        }
      }
  }
}

// ---------------------------------------------------------------- launch
extern "C" void kernel_launch(void* const* d_in, const int* in_sizes, int n_in,
                              void* d_out, int out_size, void* d_ws, size_t ws_size,
                              hipStream_t stream) {
  const float* x   = (const float*)d_in[0];
  const float* Wq  = (const float*)d_in[1];
  const float* Wkd = (const float*)d_in[2];
  const float* Wku = (const float*)d_in[3];
  const float* Wvu = (const float*)d_in[4];
  const float* Wo  = (const float*)d_in[5];
  float* out = (float*)d_out;

  char* ws = (char*)d_ws;
  bf16_t* xb   = (bf16_t*)(ws + 0);          // 8192*1024 bf16 = 16 MiB
  bf16_t* cb   = (bf16_t*)(ws + 16777216);   // 8192*64          1 MiB
  bf16_t* qtb  = (bf16_t*)(ws + 17825792);   // 8192*512         8 MiB
  bf16_t* Ub   = (bf16_t*)(ws + 26214400);   // 8192*512         8 MiB
  bf16_t* Wqe  = (bf16_t*)(ws + 34603008);   // 512*1024         1 MiB
  bf16_t* Wfe  = (bf16_t*)(ws + 35651584);   // 1024*512         1 MiB
  bf16_t* Wkdb = (bf16_t*)(ws + 36700160);   // 64*1024          128 KiB
  bf16_t* cTb  = (bf16_t*)(ws + 36831232);   // 4*64*2048        1 MiB

  cast_f32_bf16<<<8192, 256, 0, stream>>>(x, xb, BT * DM);
  cast_f32_bf16<<<64, 256, 0, stream>>>(Wkd, Wkdb, RK * DM);
  build_wq_eff<<<dim3(4, 8, 8), 256, 0, stream>>>(Wku, Wq, Wqe);
  build_w_eff<<<dim3(1024, 2), 256, 0, stream>>>(Wo, Wvu, Wfe);

  // c = x @ Wkv_down^T   [8192, 64]
  gemm_bt<bf16_t><<<dim3(BT / 128, 1), 256, 0, stream>>>(xb, Wkdb, cb, BT, RK, DM);
  // q~ = x @ Wq_eff^T    [8192, 512]  (scale pre-baked)
  gemm_bt<bf16_t><<<dim3(BT / 128, QC / 128), 256, 0, stream>>>(xb, Wqe, qtb, BT, QC, DM);
  // cT
  transpose_c<<<dim3(T_ / 64, B_), 256, 0, stream>>>(cb, cTb);
  // attention -> U [8192, 512]
  attn_kernel<<<dim3(T_ / 64, NH, B_), 256, 0, stream>>>(qtb, cb, cTb, Ub);
  // out = U @ W_eff^T    [8192, 1024] f32
  gemm_bt<float><<<dim3(BT / 128, DM / 128), 256, 0, stream>>>(Ub, Wfe, out, BT, DM, QC);
}

// Round 4
// 253.301 us; speedup vs baseline: 1.0955x; 1.0955x over previous
//
#include <hip/hip_runtime.h>
#include <hip/hip_bf16.h>
#include <math.h>

typedef __bf16 bf16_t;
typedef bf16_t bf16x8 __attribute__((ext_vector_type(8)));
typedef bf16_t bf16x4 __attribute__((ext_vector_type(4)));
typedef float f32x4 __attribute__((ext_vector_type(4)));
typedef float f32x16 __attribute__((ext_vector_type(16)));

#define DEV_INLINE __device__ __forceinline__

constexpr int B_ = 4, T_ = 2048, DM = 1024, NH = 8, RK = 64;
constexpr int BT = B_ * T_;        // 8192
constexpr int QC = NH * RK;        // 512
// softmax scale baked into Wq_eff: (1/sqrt(256)) * log2(e)
#define QK_SCALE 0.09016844f

// ---------------------------------------------------------------- cast f32->bf16
__global__ void cast_f32_bf16(const float* __restrict__ in, bf16_t* __restrict__ out, int n) {
  int i = (blockIdx.x * blockDim.x + threadIdx.x) * 4;
  if (i >= n) return;
  const float4 v = *reinterpret_cast<const float4*>(in + i);
  bf16x4 o;
  o[0] = (bf16_t)v.x; o[1] = (bf16_t)v.y; o[2] = (bf16_t)v.z; o[3] = (bf16_t)v.w;
  *reinterpret_cast<bf16x4*>(out + i) = o;
}

// ---------------------------------------------------------------- Wq_eff[(h*64+r), m] = scale * sum_d Wk_up[(h*256+d)*64+r] * Wq[(h*256+d)*1024+m]
__global__ void build_wq_eff(const float* __restrict__ Wku, const float* __restrict__ Wq,
                             bf16_t* __restrict__ out) {
  const int m = blockIdx.x * 256 + threadIdx.x;   // [0,1024)
  const int h = blockIdx.y;                       // [0,8)
  const int r0 = blockIdx.z * 8;                  // [0,64) step 8
  float s[8] = {};
  const float* wk = Wku + (size_t)h * 256 * 64 + r0;
  const float* wq = Wq + (size_t)h * 256 * 1024 + m;
  for (int d = 0; d < 256; ++d) {
    float qv = wq[(size_t)d * 1024];
#pragma unroll
    for (int j = 0; j < 8; ++j) s[j] += wk[d * 64 + j] * qv;
  }
#pragma unroll
  for (int j = 0; j < 8; ++j)
    out[(size_t)(h * 64 + r0 + j) * 1024 + m] = (bf16_t)(s[j] * QK_SCALE);
}

// ---------------------------------------------------------------- W_eff[m*512 + h*64 + r] = sum_d Wo[m*2048 + h*256 + d] * Wv_up[(h*256+d)*64 + r]
__global__ void build_w_eff(const float* __restrict__ Wo, const float* __restrict__ Wvu,
                            bf16_t* __restrict__ out) {
  const int m = blockIdx.x;                        // [0,1024)
  const int h = blockIdx.y * 4 + (threadIdx.x >> 6);
  const int r = threadIdx.x & 63;
  float s = 0.f;
  const float* wo = Wo + (size_t)m * 2048 + h * 256;
  const float* wv = Wvu + (size_t)h * 256 * 64 + r;
  for (int d = 0; d < 256; ++d) s += wo[d] * wv[d * 64];
  out[(size_t)m * 512 + h * 64 + r] = (bf16_t)s;
}

// ---------------------------------------------------------------- transpose c: cT[b][r][t] = c[b][t][r]
__global__ void transpose_c(const bf16_t* __restrict__ c, bf16_t* __restrict__ cT) {
  __shared__ bf16_t tile[64][65];
  const int b = blockIdx.y;
  const int t0 = blockIdx.x * 64;
  const int tx = threadIdx.x & 63;
  const int ty = threadIdx.x >> 6;   // 0..3
#pragma unroll
  for (int i = 0; i < 16; ++i) {
    int t = ty * 16 + i;
    tile[t][tx] = c[((size_t)b * T_ + t0 + t) * RK + tx];
  }
  __syncthreads();
#pragma unroll
  for (int i = 0; i < 16; ++i) {
    int r = ty * 16 + i;
    cT[((size_t)b * RK + r) * T_ + t0 + tx] = tile[tx][r];
  }
}

// ---------------------------------------------------------------- GEMM C[M,N] = A[M,K] * B[N,K]^T (bf16 in, f32 acc)
DEV_INLINE void storeC(float* p, float v) { *p = v; }
DEV_INLINE void storeC(bf16_t* p, float v) { *p = (bf16_t)v; }

DEV_INLINE void async_load16(const void* g, void* l) {
  __builtin_amdgcn_global_load_lds((__attribute__((address_space(1))) void*)g,
                                   (__attribute__((address_space(3))) void*)l, 16, 0, 0);
}

template <typename OutT>
__global__ __launch_bounds__(256) void gemm_bt(const bf16_t* __restrict__ A,
                                               const bf16_t* __restrict__ Bm,
                                               OutT* __restrict__ C, int M, int N, int K) {
  __shared__ bf16_t lA[128 * 32];
  __shared__ bf16_t lB[128 * 32];
  const int tid = threadIdx.x;
  const int lane = tid & 63;
  const int w = tid >> 6;
  const int lo = lane & 15, hi = lane >> 4;
  const int wr = w >> 1, wc = w & 1;
  const size_t row0 = (size_t)blockIdx.x * 128;
  const size_t col0 = (size_t)blockIdx.y * 128;
  const int w64 = w * 64;
  f32x4 acc[4][4] = {};

  for (int k0 = 0; k0 < K; k0 += 32) {
    __syncthreads();
#pragma unroll
    for (int j = 0; j < 2; ++j) {
      const int chunk = j * 256 + w64 + lane;
      const int r = chunk >> 2;
      const int kk = (chunk & 3) * 8;
      const bf16_t* gA = A + (row0 + r) * K + (k0 + kk);
      async_load16(gA, &lA[(size_t)(j * 256 + w64) * 8]);
      size_t rB = col0 + r;
      if (rB >= (size_t)N) rB = N - 1;
      const bf16_t* gB = Bm + rB * K + (k0 + kk);
      async_load16(gB, &lB[(size_t)(j * 256 + w64) * 8]);
    }
    __syncthreads();
    const bf16x8* pA = reinterpret_cast<const bf16x8*>(lA);
    const bf16x8* pB = reinterpret_cast<const bf16x8*>(lB);
    bf16x8 af[4], bfr[4];
#pragma unroll
    for (int m = 0; m < 4; ++m) af[m] = pA[(wr * 64 + m * 16 + lo) * 4 + hi];
#pragma unroll
    for (int n = 0; n < 4; ++n) bfr[n] = pB[(wc * 64 + n * 16 + lo) * 4 + hi];
#pragma unroll
    for (int m = 0; m < 4; ++m)
#pragma unroll
      for (int n = 0; n < 4; ++n)
        acc[m][n] = __builtin_amdgcn_mfma_f32_16x16x32_bf16(af[m], bfr[n], acc[m][n], 0, 0, 0);
  }
#pragma unroll
  for (int m = 0; m < 4; ++m)
#pragma unroll
    for (int n = 0; n < 4; ++n)
#pragma unroll
      for (int q = 0; q < 4; ++q) {
        const size_t row = row0 + wr * 64 + m * 16 + hi * 4 + q;
        const size_t col = col0 + wc * 64 + n * 16 + lo;
        if ((int)col < N) storeC(&C[row * N + col], acc[m][n][q]);
      }
}

// ---------------------------------------------------------------- flash attention, fully in-register softmax
// Swapped QK^T via 32x32x16 MFMA: S^T[kv][q], q = lane&31 -> softmax lane-local.
// PV computes O^T[d][q] = mfma(A = V^T (from cT), B = P packed via cvt_pk+permlane).
// Cross-half (lane^32) combines use __shfl_xor — NOT self-swap inline-asm permlane,
// which the register coalescer can collapse to v_permlane32_swap_b32 v, v (bug, r3).
// Qt [BT,512] (pre-scaled by 1/16*log2e), c [BT,64], cT [B][64][T], U [BT,512]
__global__ __launch_bounds__(256) void attn_kernel(const bf16_t* __restrict__ Qt,
                                                   const bf16_t* __restrict__ Cl,
                                                   const bf16_t* __restrict__ CT,
                                                   bf16_t* __restrict__ U) {
  const int tid = threadIdx.x;
  const int w = tid >> 6, lane = tid & 63;
  const int lq = lane & 31;        // q column owned by this lane
  const int hi = lane >> 5;        // k-half within fragments
  const int b = blockIdx.z, h = blockIdx.y;
  const size_t qrow = (size_t)b * T_ + blockIdx.x * 128 + w * 32;
  const bf16_t* __restrict__ cb = Cl + (size_t)b * T_ * RK;
  const bf16_t* __restrict__ ct = CT + (size_t)b * RK * T_;

  // Q fragments (B-operand): B[k][q], lane holds Q[q=lq][kc*16 + hi*8 + j]
  bf16x8 qf[4];
#pragma unroll
  for (int kc = 0; kc < 4; ++kc)
    qf[kc] = *reinterpret_cast<const bf16x8*>(Qt + (qrow + lq) * QC + h * RK + kc * 16 + hi * 8);

  f32x16 acc0 = {}, acc1 = {};          // O^T: d rows 0..31 / 32..63, col = q = lq
  float m_r = -INFINITY, l_r = 0.f;

  // current-tile K (A-operand rows=kv) and V^T (A-operand rows=d) fragments
  bf16x8 kf[4], vf0[2], vf1[2];
#pragma unroll
  for (int kc = 0; kc < 4; ++kc)
    kf[kc] = *reinterpret_cast<const bf16x8*>(cb + (size_t)lq * RK + kc * 16 + hi * 8);
#pragma unroll
  for (int kc = 0; kc < 2; ++kc) {
    vf0[kc] = *reinterpret_cast<const bf16x8*>(ct + (size_t)lq * T_ + kc * 16 + hi * 8);
    vf1[kc] = *reinterpret_cast<const bf16x8*>(ct + (size_t)(32 + lq) * T_ + kc * 16 + hi * 8);
  }

  for (int kv0 = 0; kv0 < T_; kv0 += 32) {
    // ---- prefetch next tile's fragments (clamped to 0 on last iter; rotated at bottom)
    const int nkv = (kv0 + 32 < T_) ? kv0 + 32 : 0;
    bf16x8 nkf[4], nvf0[2], nvf1[2];
#pragma unroll
    for (int kc = 0; kc < 4; ++kc)
      nkf[kc] = *reinterpret_cast<const bf16x8*>(cb + (size_t)(nkv + lq) * RK + kc * 16 + hi * 8);
#pragma unroll
    for (int kc = 0; kc < 2; ++kc) {
      nvf0[kc] = *reinterpret_cast<const bf16x8*>(ct + (size_t)lq * T_ + nkv + kc * 16 + hi * 8);
      nvf1[kc] = *reinterpret_cast<const bf16x8*>(ct + (size_t)(32 + lq) * T_ + nkv + kc * 16 + hi * 8);
    }

    // ---- S^T = K * Q^T : col = q (lane-local), rows = kv in regs
    f32x16 s = {};
#pragma unroll
    for (int kc = 0; kc < 4; ++kc)
      s = __builtin_amdgcn_mfma_f32_32x32x16_bf16(kf[kc], qf[kc], s, 0, 0, 0);

    // ---- tile max: in-register tree + cross-half combine via shfl_xor(32)
    float t0 = fmaxf(fmaxf(s[0], s[1]), fmaxf(s[2], s[3]));
    float t1 = fmaxf(fmaxf(s[4], s[5]), fmaxf(s[6], s[7]));
    float t2 = fmaxf(fmaxf(s[8], s[9]), fmaxf(s[10], s[11]));
    float t3 = fmaxf(fmaxf(s[12], s[13]), fmaxf(s[14], s[15]));
    float mx = fmaxf(fmaxf(t0, t1), fmaxf(t2, t3));
    mx = fmaxf(mx, __shfl_xor(mx, 32));

    // ---- T13 defer-max: rescale only when tile max exceeds running max by >8 (exp2 domain)
    if (__any(mx > m_r + 8.0f)) {
      const float mn = fmaxf(m_r, mx);
      const float al = __builtin_amdgcn_exp2f(m_r - mn);
      m_r = mn;
      l_r *= al;
#pragma unroll
      for (int i = 0; i < 16; ++i) { acc0[i] *= al; acc1[i] *= al; }
    }

    // ---- P = exp2(S - m)
    float p[16];
#pragma unroll
    for (int i = 0; i < 16; ++i) p[i] = __builtin_amdgcn_exp2f(s[i] - m_r);

    // ---- pack P to bf16 (8 cvt_pk); l accumulates the BF16-ROUNDED values
    // (bf16 view = high 16 bits as f32) so numerator/denominator are consistent.
    unsigned pw[8];
#pragma unroll
    for (int i = 0; i < 8; ++i)
      asm("v_cvt_pk_bf16_f32 %0, %1, %2" : "=v"(pw[i]) : "v"(p[2 * i]), "v"(p[2 * i + 1]));
    {
      float psum = 0.f;
#pragma unroll
      for (int i = 0; i < 8; ++i) {
        psum += __builtin_bit_cast(float, pw[i] << 16);
        psum += __builtin_bit_cast(float, pw[i] & 0xffff0000u);
      }
      l_r += psum;
    }

    // ---- redistribute P halves: permlane32_swap between DISTINCT values (safe)
    asm("v_permlane32_swap_b32 %0, %1" : "+v"(pw[0]), "+v"(pw[2]));
    asm("v_permlane32_swap_b32 %0, %1" : "+v"(pw[1]), "+v"(pw[3]));
    asm("v_permlane32_swap_b32 %0, %1" : "+v"(pw[4]), "+v"(pw[6]));
    asm("v_permlane32_swap_b32 %0, %1" : "+v"(pw[5]), "+v"(pw[7]));
    union { unsigned u[4]; bf16x8 v; } pb0, pb1;
    pb0.u[0] = pw[0]; pb0.u[1] = pw[1]; pb0.u[2] = pw[2]; pb0.u[3] = pw[3];
    pb1.u[0] = pw[4]; pb1.u[1] = pw[5]; pb1.u[2] = pw[6]; pb1.u[3] = pw[7];

    // ---- O^T += V^T * P
    acc0 = __builtin_amdgcn_mfma_f32_32x32x16_bf16(vf0[0], pb0.v, acc0, 0, 0, 0);
    acc0 = __builtin_amdgcn_mfma_f32_32x32x16_bf16(vf0[1], pb1.v, acc0, 0, 0, 0);
    acc1 = __builtin_amdgcn_mfma_f32_32x32x16_bf16(vf1[0], pb0.v, acc1, 0, 0, 0);
    acc1 = __builtin_amdgcn_mfma_f32_32x32x16_bf16(vf1[1], pb1.v, acc1, 0, 0, 0);

    // ---- rotate prefetched fragments
#pragma unroll
    for (int kc = 0; kc < 4; ++kc) kf[kc] = nkf[kc];
#pragma unroll
    for (int kc = 0; kc < 2; ++kc) { vf0[kc] = nvf0[kc]; vf1[kc] = nvf1[kc]; }
  }

  // ---- epilogue: combine partner-lane l partials (shfl_xor, not self-permlane)
  const float ltot = l_r + __shfl_xor(l_r, 32);
  const float inv = 1.0f / ltot;
  const size_t ubase = (qrow + lq) * QC + h * RK;
#pragma unroll
  for (int g = 0; g < 4; ++g) {
    bf16x4 o0, o1;
#pragma unroll
    for (int j = 0; j < 4; ++j) {
      o0[j] = (bf16_t)(acc0[g * 4 + j] * inv);
      o1[j] = (bf16_t)(acc1[g * 4 + j] * inv);
    }
    const int d0 = g * 8 + hi * 4;
    *reinterpret_cast<bf16x4*>(U + ubase + d0) = o0;
    *reinterpret_cast<bf16x4*>(U + ubase + 32 + d0) = o1;
  }
}

// ---------------------------------------------------------------- launch
extern "C" void kernel_launch(void* const* d_in, const int* in_sizes, int n_in,
                              void* d_out, int out_size, void* d_ws, size_t ws_size,
                              hipStream_t stream) {
  const float* x   = (const float*)d_in[0];
  const float* Wq  = (const float*)d_in[1];
  const float* Wkd = (const float*)d_in[2];
  const float* Wku = (const float*)d_in[3];
  const float* Wvu = (const float*)d_in[4];
  const float* Wo  = (const float*)d_in[5];
  float* out = (float*)d_out;

  char* ws = (char*)d_ws;
  bf16_t* xb   = (bf16_t*)(ws + 0);          // 8192*1024 bf16 = 16 MiB
  bf16_t* cb   = (bf16_t*)(ws + 16777216);   // 8192*64          1 MiB
  bf16_t* qtb  = (bf16_t*)(ws + 17825792);   // 8192*512         8 MiB
  bf16_t* Ub   = (bf16_t*)(ws + 26214400);   // 8192*512         8 MiB
  bf16_t* Wqe  = (bf16_t*)(ws + 34603008);   // 512*1024         1 MiB
  bf16_t* Wfe  = (bf16_t*)(ws + 35651584);   // 1024*512         1 MiB
  bf16_t* Wkdb = (bf16_t*)(ws + 36700160);   // 64*1024          128 KiB
  bf16_t* cTb  = (bf16_t*)(ws + 36831232);   // 4*64*2048        1 MiB

  cast_f32_bf16<<<8192, 256, 0, stream>>>(x, xb, BT * DM);
  cast_f32_bf16<<<64, 256, 0, stream>>>(Wkd, Wkdb, RK * DM);
  build_wq_eff<<<dim3(4, 8, 8), 256, 0, stream>>>(Wku, Wq, Wqe);
  build_w_eff<<<dim3(1024, 2), 256, 0, stream>>>(Wo, Wvu, Wfe);

  // c = x @ Wkv_down^T   [8192, 64]
  gemm_bt<bf16_t><<<dim3(BT / 128, 1), 256, 0, stream>>>(xb, Wkdb, cb, BT, RK, DM);
  // q~ = x @ Wq_eff^T    [8192, 512]  (scale pre-baked)
  gemm_bt<bf16_t><<<dim3(BT / 128, QC / 128), 256, 0, stream>>>(xb, Wqe, qtb, BT, QC, DM);
  // cT
  transpose_c<<<dim3(T_ / 64, B_), 256, 0, stream>>>(cb, cTb);
  // attention -> U [8192, 512]
  attn_kernel<<<dim3(T_ / 128, NH, B_), 256, 0, stream>>>(qtb, cb, cTb, Ub);
  // out = U @ W_eff^T    [8192, 1024] f32
  gemm_bt<float><<<dim3(BT / 128, DM / 128), 256, 0, stream>>>(Ub, Wfe, out, BT, DM, QC);
}